// Round 2
// baseline (778.385 us; speedup 1.0000x reference)
//
#include <hip/hip_runtime.h>
#include <math.h>

#define NLVL 16
#define TSIZE (1u << 19)
#define PRIME_Y 2654435761u
#define PRIME_Z 805459861u

struct ScalingsArg { float s[NLVL]; };

__device__ __forceinline__ unsigned f2bf(float f) {
    unsigned u = __float_as_uint(f);
    return (u + 0x7fffu + ((u >> 16) & 1u)) >> 16;   // RNE bf16
}
__device__ __forceinline__ float bf2f(unsigned hw) { return __uint_as_float(hw << 16); }

struct Pack { unsigned idx[8]; float wx, wy, wz; };

__device__ __forceinline__ void mkaddr(float qx, float qy, float qz, float s, Pack& P) {
    const float sx = qx * s, sy = qy * s, sz = qz * s;
    const float fx = floorf(sx), fy = floorf(sy), fz = floorf(sz);
    P.wx = sx - fx; P.wy = sy - fy; P.wz = sz - fz;
    const unsigned ixf = (unsigned)(int)fx, iyf = (unsigned)(int)fy, izf = (unsigned)(int)fz;
    const unsigned ixc = (unsigned)(int)ceilf(sx);
    const unsigned iyc = (unsigned)(int)ceilf(sy);
    const unsigned izc = (unsigned)(int)ceilf(sz);
    const unsigned hyf = iyf * PRIME_Y, hyc = iyc * PRIME_Y;
    const unsigned hzf = izf * PRIME_Z, hzc = izc * PRIME_Z;
    const unsigned m = TSIZE - 1u;
    // corner rows: 0:(c,c,c) 1:(c,f,c) 2:(f,f,c) 3:(f,c,c) 4:(c,c,f) 5:(c,f,f) 6:(f,f,f) 7:(f,c,f)
    P.idx[0] = (ixc ^ hyc ^ hzc) & m;
    P.idx[1] = (ixc ^ hyf ^ hzc) & m;
    P.idx[2] = (ixf ^ hyf ^ hzc) & m;
    P.idx[3] = (ixf ^ hyc ^ hzc) & m;
    P.idx[4] = (ixc ^ hyc ^ hzf) & m;
    P.idx[5] = (ixc ^ hyf ^ hzf) & m;
    P.idx[6] = (ixf ^ hyf ^ hzf) & m;
    P.idx[7] = (ixf ^ hyc ^ hzf) & m;
}

// ---------------- K1: encode. one thread per (point, p). depth-3 load pipeline.
// output layout: encw[l][t] = packed bf16x2 (features) for t = pt*2+p, fully coalesced.
__global__ __launch_bounds__(256, 6) void ngp_encode(
    const float* __restrict__ x,
    const float2* __restrict__ table,
    unsigned* __restrict__ encw,
    ScalingsArg sca, int npts)
{
    const int nt = npts * 2;
    const int t = blockIdx.x * 256 + threadIdx.x;
    if (t >= nt) return;
    const int pt = t >> 1, p = t & 1;
    const float* xp = x + (size_t)pt * 6 + p * 3;
    const float qx = xp[0], qy = xp[1], qz = xp[2];

    Pack P[3];
    float2 f[3][8];

    // prologue: issue levels 0 and 1
    mkaddr(qx, qy, qz, sca.s[0], P[0]);
    #pragma unroll
    for (int c = 0; c < 8; ++c) f[0][c] = table[P[0].idx[c]];
    mkaddr(qx, qy, qz, sca.s[1], P[1]);
    #pragma unroll
    for (int c = 0; c < 8; ++c) f[1][c] = table[P[1].idx[c] + TSIZE];

    #pragma unroll
    for (int l = 0; l < NLVL; ++l) {
        if (l + 2 < NLVL) {                       // issue level l+2 before consuming level l
            const int q2 = (l + 2) % 3;
            mkaddr(qx, qy, qz, sca.s[l + 2], P[q2]);
            #pragma unroll
            for (int c = 0; c < 8; ++c)
                f[q2][c] = table[P[q2].idx[c] + (unsigned)(l + 2) * TSIZE];
        }
        const int q = l % 3;
        const float wx = P[q].wx, wy = P[q].wy, wz = P[q].wz;
        const float cx = 1.f - wx, cy = 1.f - wy, cz = 1.f - wz;
        const float2 f0 = f[q][0], f1 = f[q][1], f2 = f[q][2], f3 = f[q][3];
        const float2 f4 = f[q][4], f5 = f[q][5], f6 = f[q][6], f7 = f[q][7];
        const float g03x = f0.x * wx + f3.x * cx, g03y = f0.y * wx + f3.y * cx;
        const float g12x = f1.x * wx + f2.x * cx, g12y = f1.y * wx + f2.y * cx;
        const float g56x = f5.x * wx + f6.x * cx, g56y = f5.y * wx + f6.y * cx;
        const float g47x = f4.x * wx + f7.x * cx, g47y = f4.y * wx + f7.y * cx;
        const float t0x = g03x * wy + g12x * cy, t0y = g03y * wy + g12y * cy;
        const float t1x = g47x * wy + g56x * cy, t1y = g47y * wy + g56y * cy;
        const float ex = t0x * wz + t1x * cz;
        const float ey = t0y * wz + t1y * cz;
        encw[(size_t)l * nt + t] = f2bf(ex) | (f2bf(ey) << 16);
    }
}

// ---------------- K2: MLP. one thread per point. weights staged in LDS.
__global__ __launch_bounds__(256) void ngp_mlp(
    const unsigned* __restrict__ encw,
    const float* __restrict__ w1,
    const float* __restrict__ w2,
    float* __restrict__ out, int npts)
{
    __shared__ float lw1[64 * 64];
    __shared__ float lw2[64 * 16];
    const int tid = threadIdx.x;
    #pragma unroll
    for (int i = 0; i < 16; ++i) lw1[tid + 256 * i] = w1[tid + 256 * i];
    #pragma unroll
    for (int i = 0; i < 4; ++i)  lw2[tid + 256 * i] = w2[tid + 256 * i];
    __syncthreads();

    const int pt = blockIdx.x * 256 + tid;
    if (pt >= npts) return;
    const size_t nt = (size_t)npts * 2;

    float enc[64];
    #pragma unroll
    for (int l = 0; l < NLVL; ++l) {
        const uint2 v = *reinterpret_cast<const uint2*>(&encw[(size_t)l * nt + 2 * pt]);
        enc[2 * l + 0]      = bf2f(v.x & 0xffffu);
        enc[2 * l + 1]      = bf2f(v.x >> 16);
        enc[32 + 2 * l + 0] = bf2f(v.y & 0xffffu);
        enc[32 + 2 * l + 1] = bf2f(v.y >> 16);
    }

    float o[16];
    #pragma unroll
    for (int i = 0; i < 16; ++i) o[i] = 0.f;

    for (int jb = 0; jb < 64; jb += 8) {
        float acc[8];
        #pragma unroll
        for (int jj = 0; jj < 8; ++jj) acc[jj] = 0.f;
        #pragma unroll
        for (int k = 0; k < 64; ++k) {
            const float e = enc[k];
            const float4* wrow = reinterpret_cast<const float4*>(&lw1[k * 64 + jb]);
            const float4 wa = wrow[0], wb = wrow[1];
            acc[0] += e * wa.x; acc[1] += e * wa.y; acc[2] += e * wa.z; acc[3] += e * wa.w;
            acc[4] += e * wb.x; acc[5] += e * wb.y; acc[6] += e * wb.z; acc[7] += e * wb.w;
        }
        #pragma unroll
        for (int jj = 0; jj < 8; ++jj) {
            const float hv = fmaxf(acc[jj], 0.f);
            const float4* w2row = reinterpret_cast<const float4*>(&lw2[(jb + jj) * 16]);
            const float4 wa = w2row[0], wb = w2row[1], wc = w2row[2], wd = w2row[3];
            o[0]  += hv * wa.x; o[1]  += hv * wa.y; o[2]  += hv * wa.z; o[3]  += hv * wa.w;
            o[4]  += hv * wb.x; o[5]  += hv * wb.y; o[6]  += hv * wb.z; o[7]  += hv * wb.w;
            o[8]  += hv * wc.x; o[9]  += hv * wc.y; o[10] += hv * wc.z; o[11] += hv * wc.w;
            o[12] += hv * wd.x; o[13] += hv * wd.y; o[14] += hv * wd.z; o[15] += hv * wd.w;
        }
    }

    o[0] = expf(o[0] - 1.0f);

    float4* op = reinterpret_cast<float4*>(out + (size_t)pt * 16);
    op[0] = make_float4(o[0],  o[1],  o[2],  o[3]);
    op[1] = make_float4(o[4],  o[5],  o[6],  o[7]);
    op[2] = make_float4(o[8],  o[9],  o[10], o[11]);
    op[3] = make_float4(o[12], o[13], o[14], o[15]);
}

// ---------------- fallback: round-1 fused kernel (used only if ws too small)
__global__ __launch_bounds__(256) void ngp_fused(
    const float* __restrict__ x,
    const float2* __restrict__ table,
    const float* __restrict__ w1,
    const float* __restrict__ w2,
    float* __restrict__ out,
    ScalingsArg sca, int npts)
{
    __shared__ float lw1[64 * 64];
    __shared__ float lw2[64 * 16];
    const int tid = threadIdx.x;
    #pragma unroll
    for (int i = 0; i < 16; ++i) lw1[tid + 256 * i] = w1[tid + 256 * i];
    #pragma unroll
    for (int i = 0; i < 4; ++i)  lw2[tid + 256 * i] = w2[tid + 256 * i];
    __syncthreads();

    const int gid = blockIdx.x * 256 + tid;
    if (gid >= npts) return;

    const float* xp = x + (size_t)gid * 6;
    float2 v0 = *reinterpret_cast<const float2*>(xp);
    float2 v1 = *reinterpret_cast<const float2*>(xp + 2);
    float2 v2 = *reinterpret_cast<const float2*>(xp + 4);
    float Pt[6] = { v0.x, v0.y, v1.x, v1.y, v2.x, v2.y };

    float enc[64];
    #pragma unroll
    for (int p = 0; p < 2; ++p) {
        const float qx = Pt[p * 3 + 0], qy = Pt[p * 3 + 1], qz = Pt[p * 3 + 2];
        #pragma unroll
        for (int l = 0; l < NLVL; ++l) {
            Pack P;
            mkaddr(qx, qy, qz, sca.s[l], P);
            const unsigned base = (unsigned)l * TSIZE;
            const float2 f0 = table[P.idx[0] + base];
            const float2 f1 = table[P.idx[1] + base];
            const float2 f2 = table[P.idx[2] + base];
            const float2 f3 = table[P.idx[3] + base];
            const float2 f4 = table[P.idx[4] + base];
            const float2 f5 = table[P.idx[5] + base];
            const float2 f6 = table[P.idx[6] + base];
            const float2 f7 = table[P.idx[7] + base];
            const float wx = P.wx, wy = P.wy, wz = P.wz;
            const float cx = 1.f - wx, cy = 1.f - wy, cz = 1.f - wz;
            const float g03x = f0.x * wx + f3.x * cx, g03y = f0.y * wx + f3.y * cx;
            const float g12x = f1.x * wx + f2.x * cx, g12y = f1.y * wx + f2.y * cx;
            const float g56x = f5.x * wx + f6.x * cx, g56y = f5.y * wx + f6.y * cx;
            const float g47x = f4.x * wx + f7.x * cx, g47y = f4.y * wx + f7.y * cx;
            const float t0x = g03x * wy + g12x * cy, t0y = g03y * wy + g12y * cy;
            const float t1x = g47x * wy + g56x * cy, t1y = g47y * wy + g56y * cy;
            enc[p * 32 + l * 2 + 0] = t0x * wz + t1x * cz;
            enc[p * 32 + l * 2 + 1] = t0y * wz + t1y * cz;
        }
    }

    float o[16];
    #pragma unroll
    for (int i = 0; i < 16; ++i) o[i] = 0.f;
    for (int jb = 0; jb < 64; jb += 8) {
        float acc[8];
        #pragma unroll
        for (int jj = 0; jj < 8; ++jj) acc[jj] = 0.f;
        #pragma unroll
        for (int k = 0; k < 64; ++k) {
            const float e = enc[k];
            const float4* wrow = reinterpret_cast<const float4*>(&lw1[k * 64 + jb]);
            const float4 wa = wrow[0], wb = wrow[1];
            acc[0] += e * wa.x; acc[1] += e * wa.y; acc[2] += e * wa.z; acc[3] += e * wa.w;
            acc[4] += e * wb.x; acc[5] += e * wb.y; acc[6] += e * wb.z; acc[7] += e * wb.w;
        }
        #pragma unroll
        for (int jj = 0; jj < 8; ++jj) {
            const float hv = fmaxf(acc[jj], 0.f);
            const float4* w2row = reinterpret_cast<const float4*>(&lw2[(jb + jj) * 16]);
            const float4 wa = w2row[0], wb = w2row[1], wc = w2row[2], wd = w2row[3];
            o[0]  += hv * wa.x; o[1]  += hv * wa.y; o[2]  += hv * wa.z; o[3]  += hv * wa.w;
            o[4]  += hv * wb.x; o[5]  += hv * wb.y; o[6]  += hv * wb.z; o[7]  += hv * wb.w;
            o[8]  += hv * wc.x; o[9]  += hv * wc.y; o[10] += hv * wc.z; o[11] += hv * wc.w;
            o[12] += hv * wd.x; o[13] += hv * wd.y; o[14] += hv * wd.z; o[15] += hv * wd.w;
        }
    }
    o[0] = expf(o[0] - 1.0f);
    float4* op = reinterpret_cast<float4*>(out + (size_t)gid * 16);
    op[0] = make_float4(o[0],  o[1],  o[2],  o[3]);
    op[1] = make_float4(o[4],  o[5],  o[6],  o[7]);
    op[2] = make_float4(o[8],  o[9],  o[10], o[11]);
    op[3] = make_float4(o[12], o[13], o[14], o[15]);
}

extern "C" void kernel_launch(void* const* d_in, const int* in_sizes, int n_in,
                              void* d_out, int out_size, void* d_ws, size_t ws_size,
                              hipStream_t stream) {
    const float*  x     = (const float*)d_in[0];
    const float2* table = (const float2*)d_in[1];
    const float*  w1    = (const float*)d_in[2];
    const float*  w2    = (const float*)d_in[3];
    float* out = (float*)d_out;
    const int npts = in_sizes[0] / 6;

    ScalingsArg sca;
    const double growth = exp((log(4096.0) - log(16.0)) / 15.0);
    for (int i = 0; i < NLVL; ++i)
        sca.s[i] = (float)floor(16.0 * pow(growth, (double)i));

    const size_t need = (size_t)NLVL * (size_t)npts * 2u * 4u;   // 67 MB for N=524288
    if (ws_size >= need) {
        const int nt = npts * 2;
        ngp_encode<<<(nt + 255) / 256, 256, 0, stream>>>(x, table, (unsigned*)d_ws, sca, npts);
        ngp_mlp<<<(npts + 255) / 256, 256, 0, stream>>>((const unsigned*)d_ws, w1, w2, out, npts);
    } else {
        ngp_fused<<<(npts + 255) / 256, 256, 0, stream>>>(x, table, w1, w2, out, sca, npts);
    }
}

// Round 3
// 516.168 us; speedup vs baseline: 1.5080x; 1.5080x over previous
//
#include <hip/hip_runtime.h>
#include <math.h>

#define NLVL 16
#define TSIZE (1u << 19)
#define PRIME_Y 2654435761u
#define PRIME_Z 805459861u

struct ScalingsArg { float s[NLVL]; };

__device__ __forceinline__ unsigned f2bf(float f) {
    unsigned u = __float_as_uint(f);
    return (u + 0x7fffu + ((u >> 16) & 1u)) >> 16;   // RNE bf16
}
__device__ __forceinline__ float bf2f(unsigned hw) { return __uint_as_float(hw << 16); }

struct Pack { unsigned idx[8]; float wx, wy, wz; };

__device__ __forceinline__ void mkaddr(float qx, float qy, float qz, float s, Pack& P) {
    const float sx = qx * s, sy = qy * s, sz = qz * s;
    const float fx = floorf(sx), fy = floorf(sy), fz = floorf(sz);
    P.wx = sx - fx; P.wy = sy - fy; P.wz = sz - fz;
    const unsigned ixf = (unsigned)(int)fx, iyf = (unsigned)(int)fy, izf = (unsigned)(int)fz;
    const unsigned ixc = (unsigned)(int)ceilf(sx);
    const unsigned iyc = (unsigned)(int)ceilf(sy);
    const unsigned izc = (unsigned)(int)ceilf(sz);
    const unsigned hyf = iyf * PRIME_Y, hyc = iyc * PRIME_Y;
    const unsigned hzf = izf * PRIME_Z, hzc = izc * PRIME_Z;
    const unsigned m = TSIZE - 1u;
    // corner rows: 0:(c,c,c) 1:(c,f,c) 2:(f,f,c) 3:(f,c,c) 4:(c,c,f) 5:(c,f,f) 6:(f,f,f) 7:(f,c,f)
    P.idx[0] = (ixc ^ hyc ^ hzc) & m;
    P.idx[1] = (ixc ^ hyf ^ hzc) & m;
    P.idx[2] = (ixf ^ hyf ^ hzc) & m;
    P.idx[3] = (ixf ^ hyc ^ hzc) & m;
    P.idx[4] = (ixc ^ hyc ^ hzf) & m;
    P.idx[5] = (ixc ^ hyf ^ hzf) & m;
    P.idx[6] = (ixf ^ hyf ^ hzf) & m;
    P.idx[7] = (ixf ^ hyc ^ hzf) & m;
}

__device__ __forceinline__ void interp8(const float2 f[8], float wx, float wy, float wz,
                                        float& ex, float& ey) {
    const float cx = 1.f - wx, cy = 1.f - wy, cz = 1.f - wz;
    const float g03x = f[0].x * wx + f[3].x * cx, g03y = f[0].y * wx + f[3].y * cx;
    const float g12x = f[1].x * wx + f[2].x * cx, g12y = f[1].y * wx + f[2].y * cx;
    const float g56x = f[5].x * wx + f[6].x * cx, g56y = f[5].y * wx + f[6].y * cx;
    const float g47x = f[4].x * wx + f[7].x * cx, g47y = f[4].y * wx + f[7].y * cx;
    const float t0x = g03x * wy + g12x * cy, t0y = g03y * wy + g12y * cy;
    const float t1x = g47x * wy + g56x * cy, t1y = g47y * wy + g56y * cy;
    ex = t0x * wz + t1x * cz;
    ey = t0y * wz + t1y * cz;
}

// ---------------- K0: pack table fp32 -> bf16x2 (64MB -> 32MB)
__global__ __launch_bounds__(256) void ngp_conv(
    const float4* __restrict__ t, uint2* __restrict__ o, int n2)
{
    const int i = blockIdx.x * 256 + threadIdx.x;
    if (i < n2) {
        const float4 v = t[i];
        o[i] = make_uint2(f2bf(v.x) | (f2bf(v.y) << 16),
                          f2bf(v.z) | (f2bf(v.w) << 16));
    }
}

// ---------------- K1: level-major encode. blockIdx.y = level; one thread per point
// (handles both p=0,1). BF=1: gather from bf16-packed table; BF=0: fp32 table.
template<int BF>
__global__ __launch_bounds__(256) void ngp_encode_lvl(
    const float* __restrict__ x,
    const float2* __restrict__ tf,
    const unsigned* __restrict__ tb,
    unsigned* __restrict__ encu,
    ScalingsArg sca, int npts)
{
    const int pt = blockIdx.x * 256 + threadIdx.x;
    if (pt >= npts) return;
    const int l = blockIdx.y;
    const float s = sca.s[l];

    const float* xp = x + (size_t)pt * 6;
    const float2 v0 = *reinterpret_cast<const float2*>(xp);
    const float2 v1 = *reinterpret_cast<const float2*>(xp + 2);
    const float2 v2 = *reinterpret_cast<const float2*>(xp + 4);

    Pack P0, P1;
    mkaddr(v0.x, v0.y, v1.x, s, P0);
    mkaddr(v1.y, v2.x, v2.y, s, P1);
    const unsigned base = (unsigned)l * TSIZE;

    float2 f0[8], f1[8];
    if (BF) {
        unsigned g0[8], g1[8];
        #pragma unroll
        for (int c = 0; c < 8; ++c) g0[c] = tb[P0.idx[c] + base];
        #pragma unroll
        for (int c = 0; c < 8; ++c) g1[c] = tb[P1.idx[c] + base];
        #pragma unroll
        for (int c = 0; c < 8; ++c) {
            f0[c] = make_float2(bf2f(g0[c] & 0xffffu), bf2f(g0[c] >> 16));
            f1[c] = make_float2(bf2f(g1[c] & 0xffffu), bf2f(g1[c] >> 16));
        }
    } else {
        #pragma unroll
        for (int c = 0; c < 8; ++c) f0[c] = tf[P0.idx[c] + base];
        #pragma unroll
        for (int c = 0; c < 8; ++c) f1[c] = tf[P1.idx[c] + base];
    }

    float e0x, e0y, e1x, e1y;
    interp8(f0, P0.wx, P0.wy, P0.wz, e0x, e0y);
    interp8(f1, P1.wx, P1.wy, P1.wz, e1x, e1y);

    const uint2 r = make_uint2(f2bf(e0x) | (f2bf(e0y) << 16),
                               f2bf(e1x) | (f2bf(e1y) << 16));
    *reinterpret_cast<uint2*>(&encu[(size_t)l * ((size_t)npts * 2) + 2 * pt]) = r;
}

// ---------------- K2: MLP. one thread per point. weights staged in LDS.
__global__ __launch_bounds__(256) void ngp_mlp(
    const unsigned* __restrict__ encw,
    const float* __restrict__ w1,
    const float* __restrict__ w2,
    float* __restrict__ out, int npts)
{
    __shared__ float lw1[64 * 64];
    __shared__ float lw2[64 * 16];
    const int tid = threadIdx.x;
    #pragma unroll
    for (int i = 0; i < 16; ++i) lw1[tid + 256 * i] = w1[tid + 256 * i];
    #pragma unroll
    for (int i = 0; i < 4; ++i)  lw2[tid + 256 * i] = w2[tid + 256 * i];
    __syncthreads();

    const int pt = blockIdx.x * 256 + tid;
    if (pt >= npts) return;
    const size_t nt = (size_t)npts * 2;

    float enc[64];
    #pragma unroll
    for (int l = 0; l < NLVL; ++l) {
        const uint2 v = *reinterpret_cast<const uint2*>(&encw[(size_t)l * nt + 2 * pt]);
        enc[2 * l + 0]      = bf2f(v.x & 0xffffu);
        enc[2 * l + 1]      = bf2f(v.x >> 16);
        enc[32 + 2 * l + 0] = bf2f(v.y & 0xffffu);
        enc[32 + 2 * l + 1] = bf2f(v.y >> 16);
    }

    float o[16];
    #pragma unroll
    for (int i = 0; i < 16; ++i) o[i] = 0.f;

    for (int jb = 0; jb < 64; jb += 8) {
        float acc[8];
        #pragma unroll
        for (int jj = 0; jj < 8; ++jj) acc[jj] = 0.f;
        #pragma unroll
        for (int k = 0; k < 64; ++k) {
            const float e = enc[k];
            const float4* wrow = reinterpret_cast<const float4*>(&lw1[k * 64 + jb]);
            const float4 wa = wrow[0], wb = wrow[1];
            acc[0] += e * wa.x; acc[1] += e * wa.y; acc[2] += e * wa.z; acc[3] += e * wa.w;
            acc[4] += e * wb.x; acc[5] += e * wb.y; acc[6] += e * wb.z; acc[7] += e * wb.w;
        }
        #pragma unroll
        for (int jj = 0; jj < 8; ++jj) {
            const float hv = fmaxf(acc[jj], 0.f);
            const float4* w2row = reinterpret_cast<const float4*>(&lw2[(jb + jj) * 16]);
            const float4 wa = w2row[0], wb = w2row[1], wc = w2row[2], wd = w2row[3];
            o[0]  += hv * wa.x; o[1]  += hv * wa.y; o[2]  += hv * wa.z; o[3]  += hv * wa.w;
            o[4]  += hv * wb.x; o[5]  += hv * wb.y; o[6]  += hv * wb.z; o[7]  += hv * wb.w;
            o[8]  += hv * wc.x; o[9]  += hv * wc.y; o[10] += hv * wc.z; o[11] += hv * wc.w;
            o[12] += hv * wd.x; o[13] += hv * wd.y; o[14] += hv * wd.z; o[15] += hv * wd.w;
        }
    }

    o[0] = expf(o[0] - 1.0f);

    float4* op = reinterpret_cast<float4*>(out + (size_t)pt * 16);
    op[0] = make_float4(o[0],  o[1],  o[2],  o[3]);
    op[1] = make_float4(o[4],  o[5],  o[6],  o[7]);
    op[2] = make_float4(o[8],  o[9],  o[10], o[11]);
    op[3] = make_float4(o[12], o[13], o[14], o[15]);
}

// ---------------- fallback: fully fused single kernel (only if ws too small)
__global__ __launch_bounds__(256) void ngp_fused(
    const float* __restrict__ x,
    const float2* __restrict__ table,
    const float* __restrict__ w1,
    const float* __restrict__ w2,
    float* __restrict__ out,
    ScalingsArg sca, int npts)
{
    __shared__ float lw1[64 * 64];
    __shared__ float lw2[64 * 16];
    const int tid = threadIdx.x;
    #pragma unroll
    for (int i = 0; i < 16; ++i) lw1[tid + 256 * i] = w1[tid + 256 * i];
    #pragma unroll
    for (int i = 0; i < 4; ++i)  lw2[tid + 256 * i] = w2[tid + 256 * i];
    __syncthreads();

    const int gid = blockIdx.x * 256 + tid;
    if (gid >= npts) return;

    const float* xp = x + (size_t)gid * 6;
    float2 v0 = *reinterpret_cast<const float2*>(xp);
    float2 v1 = *reinterpret_cast<const float2*>(xp + 2);
    float2 v2 = *reinterpret_cast<const float2*>(xp + 4);
    float Pt[6] = { v0.x, v0.y, v1.x, v1.y, v2.x, v2.y };

    float enc[64];
    #pragma unroll
    for (int p = 0; p < 2; ++p) {
        const float qx = Pt[p * 3 + 0], qy = Pt[p * 3 + 1], qz = Pt[p * 3 + 2];
        #pragma unroll
        for (int l = 0; l < NLVL; ++l) {
            Pack P;
            mkaddr(qx, qy, qz, sca.s[l], P);
            const unsigned base = (unsigned)l * TSIZE;
            float2 f[8];
            #pragma unroll
            for (int c = 0; c < 8; ++c) f[c] = table[P.idx[c] + base];
            float ex, ey;
            interp8(f, P.wx, P.wy, P.wz, ex, ey);
            enc[p * 32 + l * 2 + 0] = ex;
            enc[p * 32 + l * 2 + 1] = ey;
        }
    }

    float o[16];
    #pragma unroll
    for (int i = 0; i < 16; ++i) o[i] = 0.f;
    for (int jb = 0; jb < 64; jb += 8) {
        float acc[8];
        #pragma unroll
        for (int jj = 0; jj < 8; ++jj) acc[jj] = 0.f;
        #pragma unroll
        for (int k = 0; k < 64; ++k) {
            const float e = enc[k];
            const float4* wrow = reinterpret_cast<const float4*>(&lw1[k * 64 + jb]);
            const float4 wa = wrow[0], wb = wrow[1];
            acc[0] += e * wa.x; acc[1] += e * wa.y; acc[2] += e * wa.z; acc[3] += e * wa.w;
            acc[4] += e * wb.x; acc[5] += e * wb.y; acc[6] += e * wb.z; acc[7] += e * wb.w;
        }
        #pragma unroll
        for (int jj = 0; jj < 8; ++jj) {
            const float hv = fmaxf(acc[jj], 0.f);
            const float4* w2row = reinterpret_cast<const float4*>(&lw2[(jb + jj) * 16]);
            const float4 wa = w2row[0], wb = w2row[1], wc = w2row[2], wd = w2row[3];
            o[0]  += hv * wa.x; o[1]  += hv * wa.y; o[2]  += hv * wa.z; o[3]  += hv * wa.w;
            o[4]  += hv * wb.x; o[5]  += hv * wb.y; o[6]  += hv * wb.z; o[7]  += hv * wb.w;
            o[8]  += hv * wc.x; o[9]  += hv * wc.y; o[10] += hv * wc.z; o[11] += hv * wc.w;
            o[12] += hv * wd.x; o[13] += hv * wd.y; o[14] += hv * wd.z; o[15] += hv * wd.w;
        }
    }
    o[0] = expf(o[0] - 1.0f);
    float4* op = reinterpret_cast<float4*>(out + (size_t)gid * 16);
    op[0] = make_float4(o[0],  o[1],  o[2],  o[3]);
    op[1] = make_float4(o[4],  o[5],  o[6],  o[7]);
    op[2] = make_float4(o[8],  o[9],  o[10], o[11]);
    op[3] = make_float4(o[12], o[13], o[14], o[15]);
}

extern "C" void kernel_launch(void* const* d_in, const int* in_sizes, int n_in,
                              void* d_out, int out_size, void* d_ws, size_t ws_size,
                              hipStream_t stream) {
    const float*  x     = (const float*)d_in[0];
    const float2* table = (const float2*)d_in[1];
    const float*  w1    = (const float*)d_in[2];
    const float*  w2    = (const float*)d_in[3];
    float* out = (float*)d_out;
    const int npts = in_sizes[0] / 6;

    ScalingsArg sca;
    const double growth = exp((log(4096.0) - log(16.0)) / 15.0);
    for (int i = 0; i < NLVL; ++i)
        sca.s[i] = (float)floor(16.0 * pow(growth, (double)i));

    const size_t tbl_bytes = (size_t)NLVL * TSIZE * 4u;              // 32 MB
    const size_t enc_bytes = (size_t)NLVL * (size_t)npts * 2u * 4u;  // 67 MB
    const int bpl = (npts + 255) / 256;
    const dim3 gEnc(bpl, NLVL);

    if (ws_size >= tbl_bytes + enc_bytes) {
        // path A: bf16 table + level-major encode
        unsigned* tb  = (unsigned*)d_ws;
        unsigned* enc = (unsigned*)((char*)d_ws + tbl_bytes);
        const int n2 = (NLVL * TSIZE) / 2;
        ngp_conv<<<(n2 + 255) / 256, 256, 0, stream>>>((const float4*)table, (uint2*)tb, n2);
        ngp_encode_lvl<1><<<gEnc, 256, 0, stream>>>(x, nullptr, tb, enc, sca, npts);
        ngp_mlp<<<(npts + 255) / 256, 256, 0, stream>>>(enc, w1, w2, out, npts);
    } else if (ws_size >= enc_bytes) {
        // path B: fp32 table + level-major encode
        unsigned* enc = (unsigned*)d_ws;
        ngp_encode_lvl<0><<<gEnc, 256, 0, stream>>>(x, table, nullptr, enc, sca, npts);
        ngp_mlp<<<(npts + 255) / 256, 256, 0, stream>>>(enc, w1, w2, out, npts);
    } else {
        ngp_fused<<<(npts + 255) / 256, 256, 0, stream>>>(x, table, w1, w2, out, sca, npts);
    }
}

// Round 4
// 449.723 us; speedup vs baseline: 1.7308x; 1.1477x over previous
//
#include <hip/hip_runtime.h>
#include <math.h>

#define NLVL 16
#define TSIZE (1u << 19)
#define PRIME_Y 2654435761u
#define PRIME_Z 805459861u

struct ScalingsArg { float s[NLVL]; };

__device__ __forceinline__ unsigned f2bf(float f) {
    unsigned u = __float_as_uint(f);
    return (u + 0x7fffu + ((u >> 16) & 1u)) >> 16;   // RNE bf16
}
__device__ __forceinline__ float bf2f(unsigned hw) { return __uint_as_float(hw << 16); }

// ---------------- K0: pack table fp32 -> bf16x2 (64MB -> 32MB) [path A only]
__global__ __launch_bounds__(256) void ngp_conv(
    const float4* __restrict__ t, uint2* __restrict__ o, int n2)
{
    const int i = blockIdx.x * 256 + threadIdx.x;
    if (i < n2) {
        const float4 v = t[i];
        o[i] = make_uint2(f2bf(v.x) | (f2bf(v.y) << 16),
                          f2bf(v.z) | (f2bf(v.w) << 16));
    }
}

// ---------------- K1: level-major encode with x-pair merged gathers.
// PRIME_x == 1 => corner pair along x has indices {A, A^dx}, dx = ixf^ixc.
// dx==1 (p=1/2): both corners in one aligned 2-entry block -> single load.
// BF=1: bf16 table (4B entries; dx==1 -> 8B load, dx==3 -> 16B load).
// BF=0: fp32 table (8B entries; dx==1 -> 16B load).
template<int BF>
__global__ __launch_bounds__(256) void ngp_encode_lvl(
    const float* __restrict__ x,
    const float2* __restrict__ tf,
    const unsigned* __restrict__ tb,
    unsigned* __restrict__ encu,
    ScalingsArg sca, int npts)
{
    const int pt = blockIdx.x * 256 + threadIdx.x;
    if (pt >= npts) return;
    const int l = blockIdx.y;
    const float s = sca.s[l];
    const unsigned base = (unsigned)l * TSIZE;
    const unsigned m = TSIZE - 1u;

    const float* xp = x + (size_t)pt * 6;
    const float2 v0 = *reinterpret_cast<const float2*>(xp);
    const float2 v1 = *reinterpret_cast<const float2*>(xp + 2);
    const float2 v2 = *reinterpret_cast<const float2*>(xp + 4);
    const float q[2][3] = { { v0.x, v0.y, v1.x }, { v1.y, v2.x, v2.y } };

    unsigned rout[2];
    #pragma unroll
    for (int e = 0; e < 2; ++e) {
        const float sx = q[e][0] * s, sy = q[e][1] * s, sz = q[e][2] * s;
        const float fx = floorf(sx), fy = floorf(sy), fz = floorf(sz);
        const float wx = sx - fx, wy = sy - fy, wz = sz - fz;
        const unsigned ixf = (unsigned)(int)fx, iyf = (unsigned)(int)fy, izf = (unsigned)(int)fz;
        const unsigned ixc = (unsigned)(int)ceilf(sx);
        const unsigned iyc = (unsigned)(int)ceilf(sy);
        const unsigned izc = (unsigned)(int)ceilf(sz);
        const unsigned hyf = iyf * PRIME_Y, hyc = iyc * PRIME_Y;
        const unsigned hzf = izf * PRIME_Z, hzc = izc * PRIME_Z;
        // pair j holds corners (c=ixc, f=ixf) at y/z combo:
        // j=0:(yc,zc)->corners 0/3  j=1:(yf,zc)->1/2  j=2:(yf,zf)->5/6  j=3:(yc,zf)->4/7
        const unsigned h0 = hyc ^ hzc, h1 = hyf ^ hzc, h2 = hyf ^ hzf, h3 = hyc ^ hzf;
        const unsigned dx = ixf ^ ixc;
        const unsigned A[4] = { (ixf ^ h0) & m, (ixf ^ h1) & m,
                                (ixf ^ h2) & m, (ixf ^ h3) & m };

        float2 cf[4], cc[4];   // f-corner / c-corner feature pairs

        if (BF) {
            unsigned uf[4], uc[4];
            if (dx == 1u) {
                #pragma unroll
                for (int j = 0; j < 4; ++j) {
                    const uint2 v = *reinterpret_cast<const uint2*>(&tb[base + (A[j] & ~1u)]);
                    const bool hi = (A[j] & 1u) != 0u;
                    uf[j] = hi ? v.y : v.x;
                    uc[j] = hi ? v.x : v.y;
                }
            } else if (dx == 3u) {
                #pragma unroll
                for (int j = 0; j < 4; ++j) {
                    const uint4 v = *reinterpret_cast<const uint4*>(&tb[base + (A[j] & ~3u)]);
                    const unsigned o = A[j] & 3u;
                    uf[j] = (o == 0u) ? v.x : (o == 1u) ? v.y : (o == 2u) ? v.z : v.w;
                    uc[j] = (o == 0u) ? v.w : (o == 1u) ? v.z : (o == 2u) ? v.y : v.x;
                }
            } else {
                #pragma unroll
                for (int j = 0; j < 4; ++j) {
                    uf[j] = tb[base + A[j]];
                    uc[j] = tb[base + ((A[j] ^ dx) & m)];
                }
            }
            #pragma unroll
            for (int j = 0; j < 4; ++j) {
                cf[j] = make_float2(bf2f(uf[j] & 0xffffu), bf2f(uf[j] >> 16));
                cc[j] = make_float2(bf2f(uc[j] & 0xffffu), bf2f(uc[j] >> 16));
            }
        } else {
            if (dx == 1u) {
                #pragma unroll
                for (int j = 0; j < 4; ++j) {
                    const float4 v = *reinterpret_cast<const float4*>(&tf[base + (A[j] & ~1u)]);
                    const bool hi = (A[j] & 1u) != 0u;
                    cf[j] = hi ? make_float2(v.z, v.w) : make_float2(v.x, v.y);
                    cc[j] = hi ? make_float2(v.x, v.y) : make_float2(v.z, v.w);
                }
            } else {
                #pragma unroll
                for (int j = 0; j < 4; ++j) {
                    cf[j] = tf[base + A[j]];
                    cc[j] = tf[base + ((A[j] ^ dx) & m)];
                }
            }
        }

        // trilinear lerp; c-corner weight wx, f-corner weight (1-wx), per reference
        const float cx = 1.f - wx, cy = 1.f - wy, cz = 1.f - wz;
        const float g03x = cc[0].x * wx + cf[0].x * cx, g03y = cc[0].y * wx + cf[0].y * cx;
        const float g12x = cc[1].x * wx + cf[1].x * cx, g12y = cc[1].y * wx + cf[1].y * cx;
        const float g56x = cc[2].x * wx + cf[2].x * cx, g56y = cc[2].y * wx + cf[2].y * cx;
        const float g47x = cc[3].x * wx + cf[3].x * cx, g47y = cc[3].y * wx + cf[3].y * cx;
        const float t0x = g03x * wy + g12x * cy, t0y = g03y * wy + g12y * cy;
        const float t1x = g47x * wy + g56x * cy, t1y = g47y * wy + g56y * cy;
        const float ex = t0x * wz + t1x * cz;
        const float ey = t0y * wz + t1y * cz;
        rout[e] = f2bf(ex) | (f2bf(ey) << 16);
    }

    *reinterpret_cast<uint2*>(&encu[(size_t)l * ((size_t)npts * 2) + 2 * pt]) =
        make_uint2(rout[0], rout[1]);
}

// ---------------- K2: MLP. one thread per point. weights staged in LDS.
__global__ __launch_bounds__(256) void ngp_mlp(
    const unsigned* __restrict__ encw,
    const float* __restrict__ w1,
    const float* __restrict__ w2,
    float* __restrict__ out, int npts)
{
    __shared__ float lw1[64 * 64];
    __shared__ float lw2[64 * 16];
    const int tid = threadIdx.x;
    #pragma unroll
    for (int i = 0; i < 16; ++i) lw1[tid + 256 * i] = w1[tid + 256 * i];
    #pragma unroll
    for (int i = 0; i < 4; ++i)  lw2[tid + 256 * i] = w2[tid + 256 * i];
    __syncthreads();

    const int pt = blockIdx.x * 256 + tid;
    if (pt >= npts) return;
    const size_t nt = (size_t)npts * 2;

    float enc[64];
    #pragma unroll
    for (int l = 0; l < NLVL; ++l) {
        const uint2 v = *reinterpret_cast<const uint2*>(&encw[(size_t)l * nt + 2 * pt]);
        enc[2 * l + 0]      = bf2f(v.x & 0xffffu);
        enc[2 * l + 1]      = bf2f(v.x >> 16);
        enc[32 + 2 * l + 0] = bf2f(v.y & 0xffffu);
        enc[32 + 2 * l + 1] = bf2f(v.y >> 16);
    }

    float o[16];
    #pragma unroll
    for (int i = 0; i < 16; ++i) o[i] = 0.f;

    for (int jb = 0; jb < 64; jb += 8) {
        float acc[8];
        #pragma unroll
        for (int jj = 0; jj < 8; ++jj) acc[jj] = 0.f;
        #pragma unroll
        for (int k = 0; k < 64; ++k) {
            const float e = enc[k];
            const float4* wrow = reinterpret_cast<const float4*>(&lw1[k * 64 + jb]);
            const float4 wa = wrow[0], wb = wrow[1];
            acc[0] += e * wa.x; acc[1] += e * wa.y; acc[2] += e * wa.z; acc[3] += e * wa.w;
            acc[4] += e * wb.x; acc[5] += e * wb.y; acc[6] += e * wb.z; acc[7] += e * wb.w;
        }
        #pragma unroll
        for (int jj = 0; jj < 8; ++jj) {
            const float hv = fmaxf(acc[jj], 0.f);
            const float4* w2row = reinterpret_cast<const float4*>(&lw2[(jb + jj) * 16]);
            const float4 wa = w2row[0], wb = w2row[1], wc = w2row[2], wd = w2row[3];
            o[0]  += hv * wa.x; o[1]  += hv * wa.y; o[2]  += hv * wa.z; o[3]  += hv * wa.w;
            o[4]  += hv * wb.x; o[5]  += hv * wb.y; o[6]  += hv * wb.z; o[7]  += hv * wb.w;
            o[8]  += hv * wc.x; o[9]  += hv * wc.y; o[10] += hv * wc.z; o[11] += hv * wc.w;
            o[12] += hv * wd.x; o[13] += hv * wd.y; o[14] += hv * wd.z; o[15] += hv * wd.w;
        }
    }

    o[0] = expf(o[0] - 1.0f);

    float4* op = reinterpret_cast<float4*>(out + (size_t)pt * 16);
    op[0] = make_float4(o[0],  o[1],  o[2],  o[3]);
    op[1] = make_float4(o[4],  o[5],  o[6],  o[7]);
    op[2] = make_float4(o[8],  o[9],  o[10], o[11]);
    op[3] = make_float4(o[12], o[13], o[14], o[15]);
}

// ---------------- fallback: fully fused single kernel (only if ws too small)
__global__ __launch_bounds__(256) void ngp_fused(
    const float* __restrict__ x,
    const float2* __restrict__ table,
    const float* __restrict__ w1,
    const float* __restrict__ w2,
    float* __restrict__ out,
    ScalingsArg sca, int npts)
{
    __shared__ float lw1[64 * 64];
    __shared__ float lw2[64 * 16];
    const int tid = threadIdx.x;
    #pragma unroll
    for (int i = 0; i < 16; ++i) lw1[tid + 256 * i] = w1[tid + 256 * i];
    #pragma unroll
    for (int i = 0; i < 4; ++i)  lw2[tid + 256 * i] = w2[tid + 256 * i];
    __syncthreads();

    const int gid = blockIdx.x * 256 + tid;
    if (gid >= npts) return;

    const float* xp = x + (size_t)gid * 6;
    float2 v0 = *reinterpret_cast<const float2*>(xp);
    float2 v1 = *reinterpret_cast<const float2*>(xp + 2);
    float2 v2 = *reinterpret_cast<const float2*>(xp + 4);
    float Pt[6] = { v0.x, v0.y, v1.x, v1.y, v2.x, v2.y };

    float enc[64];
    #pragma unroll
    for (int p = 0; p < 2; ++p) {
        const float qx = Pt[p * 3 + 0], qy = Pt[p * 3 + 1], qz = Pt[p * 3 + 2];
        #pragma unroll
        for (int l = 0; l < NLVL; ++l) {
            const float s = sca.s[l];
            const float sx = qx * s, sy = qy * s, sz = qz * s;
            const float fx = floorf(sx), fy = floorf(sy), fz = floorf(sz);
            const float wx = sx - fx, wy = sy - fy, wz = sz - fz;
            const unsigned ixf = (unsigned)(int)fx, iyf = (unsigned)(int)fy, izf = (unsigned)(int)fz;
            const unsigned ixc = (unsigned)(int)ceilf(sx);
            const unsigned iyc = (unsigned)(int)ceilf(sy);
            const unsigned izc = (unsigned)(int)ceilf(sz);
            const unsigned hyf = iyf * PRIME_Y, hyc = iyc * PRIME_Y;
            const unsigned hzf = izf * PRIME_Z, hzc = izc * PRIME_Z;
            const unsigned mm = TSIZE - 1u;
            const unsigned bs = (unsigned)l * TSIZE;
            const float2 f0 = table[((ixc ^ hyc ^ hzc) & mm) + bs];
            const float2 f1 = table[((ixc ^ hyf ^ hzc) & mm) + bs];
            const float2 f2 = table[((ixf ^ hyf ^ hzc) & mm) + bs];
            const float2 f3 = table[((ixf ^ hyc ^ hzc) & mm) + bs];
            const float2 f4 = table[((ixc ^ hyc ^ hzf) & mm) + bs];
            const float2 f5 = table[((ixc ^ hyf ^ hzf) & mm) + bs];
            const float2 f6 = table[((ixf ^ hyf ^ hzf) & mm) + bs];
            const float2 f7 = table[((ixf ^ hyc ^ hzf) & mm) + bs];
            const float cx = 1.f - wx, cy = 1.f - wy, cz = 1.f - wz;
            const float g03x = f0.x * wx + f3.x * cx, g03y = f0.y * wx + f3.y * cx;
            const float g12x = f1.x * wx + f2.x * cx, g12y = f1.y * wx + f2.y * cx;
            const float g56x = f5.x * wx + f6.x * cx, g56y = f5.y * wx + f6.y * cx;
            const float g47x = f4.x * wx + f7.x * cx, g47y = f4.y * wx + f7.y * cx;
            const float t0x = g03x * wy + g12x * cy, t0y = g03y * wy + g12y * cy;
            const float t1x = g47x * wy + g56x * cy, t1y = g47y * wy + g56y * cy;
            enc[p * 32 + l * 2 + 0] = t0x * wz + t1x * cz;
            enc[p * 32 + l * 2 + 1] = t0y * wz + t1y * cz;
        }
    }

    float o[16];
    #pragma unroll
    for (int i = 0; i < 16; ++i) o[i] = 0.f;
    for (int jb = 0; jb < 64; jb += 8) {
        float acc[8];
        #pragma unroll
        for (int jj = 0; jj < 8; ++jj) acc[jj] = 0.f;
        #pragma unroll
        for (int k = 0; k < 64; ++k) {
            const float e = enc[k];
            const float4* wrow = reinterpret_cast<const float4*>(&lw1[k * 64 + jb]);
            const float4 wa = wrow[0], wb = wrow[1];
            acc[0] += e * wa.x; acc[1] += e * wa.y; acc[2] += e * wa.z; acc[3] += e * wa.w;
            acc[4] += e * wb.x; acc[5] += e * wb.y; acc[6] += e * wb.z; acc[7] += e * wb.w;
        }
        #pragma unroll
        for (int jj = 0; jj < 8; ++jj) {
            const float hv = fmaxf(acc[jj], 0.f);
            const float4* w2row = reinterpret_cast<const float4*>(&lw2[(jb + jj) * 16]);
            const float4 wa = w2row[0], wb = w2row[1], wc = w2row[2], wd = w2row[3];
            o[0]  += hv * wa.x; o[1]  += hv * wa.y; o[2]  += hv * wa.z; o[3]  += hv * wa.w;
            o[4]  += hv * wb.x; o[5]  += hv * wb.y; o[6]  += hv * wb.z; o[7]  += hv * wb.w;
            o[8]  += hv * wc.x; o[9]  += hv * wc.y; o[10] += hv * wc.z; o[11] += hv * wc.w;
            o[12] += hv * wd.x; o[13] += hv * wd.y; o[14] += hv * wd.z; o[15] += hv * wd.w;
        }
    }
    o[0] = expf(o[0] - 1.0f);
    float4* op = reinterpret_cast<float4*>(out + (size_t)gid * 16);
    op[0] = make_float4(o[0],  o[1],  o[2],  o[3]);
    op[1] = make_float4(o[4],  o[5],  o[6],  o[7]);
    op[2] = make_float4(o[8],  o[9],  o[10], o[11]);
    op[3] = make_float4(o[12], o[13], o[14], o[15]);
}

extern "C" void kernel_launch(void* const* d_in, const int* in_sizes, int n_in,
                              void* d_out, int out_size, void* d_ws, size_t ws_size,
                              hipStream_t stream) {
    const float*  x     = (const float*)d_in[0];
    const float2* table = (const float2*)d_in[1];
    const float*  w1    = (const float*)d_in[2];
    const float*  w2    = (const float*)d_in[3];
    float* out = (float*)d_out;
    const int npts = in_sizes[0] / 6;

    ScalingsArg sca;
    const double growth = exp((log(4096.0) - log(16.0)) / 15.0);
    for (int i = 0; i < NLVL; ++i)
        sca.s[i] = (float)floor(16.0 * pow(growth, (double)i));

    const size_t tbl_bytes = (size_t)NLVL * TSIZE * 4u;              // 32 MB
    const size_t enc_bytes = (size_t)NLVL * (size_t)npts * 2u * 4u;  // 67 MB
    const int bpl = (npts + 255) / 256;
    const dim3 gEnc(bpl, NLVL);

    if (ws_size >= tbl_bytes + enc_bytes) {
        // path A: bf16 table + level-major encode (dx==1 and dx==3 merging)
        unsigned* tb  = (unsigned*)d_ws;
        unsigned* enc = (unsigned*)((char*)d_ws + tbl_bytes);
        const int n2 = (NLVL * TSIZE) / 2;
        ngp_conv<<<(n2 + 255) / 256, 256, 0, stream>>>((const float4*)table, (uint2*)tb, n2);
        ngp_encode_lvl<1><<<gEnc, 256, 0, stream>>>(x, nullptr, tb, enc, sca, npts);
        ngp_mlp<<<(npts + 255) / 256, 256, 0, stream>>>(enc, w1, w2, out, npts);
    } else if (ws_size >= enc_bytes) {
        // path B: fp32 table + level-major encode (dx==1 merging via float4)
        unsigned* enc = (unsigned*)d_ws;
        ngp_encode_lvl<0><<<gEnc, 256, 0, stream>>>(x, table, nullptr, enc, sca, npts);
        ngp_mlp<<<(npts + 255) / 256, 256, 0, stream>>>(enc, w1, w2, out, npts);
    } else {
        ngp_fused<<<(npts + 255) / 256, 256, 0, stream>>>(x, table, w1, w2, out, sca, npts);
    }
}